// Round 2
// baseline (1036.281 us; speedup 1.0000x reference)
//
#include <hip/hip_runtime.h>

typedef unsigned short u16;
typedef unsigned int u32;
typedef _Float16 f16;

using half8 = __attribute__((ext_vector_type(8))) _Float16;
using f32x4 = __attribute__((ext_vector_type(4))) float;

__device__ __forceinline__ void async16(const void* g, void* l) {
    __builtin_amdgcn_global_load_lds(
        (const __attribute__((address_space(1))) u32*)g,
        (__attribute__((address_space(3))) u32*)l, 16, 0, 0);
}

// ---------------------------------------------------------------------------
// Prep 1: P1 = feats @ W1a, P2 = feats @ W1b   (4096 x 512 fp32 each)
// feats[n][cell][c] = img[n][c][cell] for c<64; c=64 -> cell/8; c=65 -> cell%8
// grid 512 blocks (8 cells each), block 512
// ---------------------------------------------------------------------------
__global__ __launch_bounds__(512) void prep_p12(const float* __restrict__ img,
                                                const float* __restrict__ gw1,
                                                float* __restrict__ P1,
                                                float* __restrict__ P2) {
    const int blk = blockIdx.x;
    const int n = blk >> 3;
    const int c0 = (blk & 7) * 8;
    const int t = threadIdx.x;
    __shared__ float feats[8][68];
    for (int idx = t; idx < 8 * 66; idx += 512) {
        int rr = idx / 66, cc = idx % 66, cell = c0 + rr;
        float v;
        if (cc < 64)       v = img[((size_t)(n * 64 + cc)) * 64 + cell];
        else if (cc == 64) v = (float)(cell >> 3);
        else               v = (float)(cell & 7);
        feats[rr][cc] = v;
    }
    __syncthreads();
    const int g = t;
    float a1[8], a2[8];
#pragma unroll
    for (int r = 0; r < 8; ++r) { a1[r] = 0.f; a2[r] = 0.f; }
    for (int c = 0; c < 66; ++c) {
        float wa = gw1[(size_t)c * 512 + g];
        float wb = gw1[(size_t)(66 + c) * 512 + g];
#pragma unroll
        for (int r = 0; r < 8; ++r) {
            a1[r] += feats[r][c] * wa;
            a2[r] += feats[r][c] * wb;
        }
    }
#pragma unroll
    for (int r = 0; r < 8; ++r) {
        P1[((size_t)(n * 64 + c0 + r)) * 512 + g] = a1[r];
        P2[((size_t)(n * 64 + c0 + r)) * 512 + g] = a2[r];
    }
}

// ---------------------------------------------------------------------------
// Prep 2: Qc[n] = ques[n] @ W1c + b1  (64 x 512 fp32); also zero context.
// grid 64, block 512
// ---------------------------------------------------------------------------
__global__ __launch_bounds__(512) void prep_q(const float* __restrict__ ques,
                                              const float* __restrict__ gw1,
                                              const float* __restrict__ gb1,
                                              float* __restrict__ Qc,
                                              float* __restrict__ Ctx) {
    const int n = blockIdx.x;
    const int t = threadIdx.x;
    __shared__ float q[256];
    if (t < 256) q[t] = ques[(size_t)n * 256 + t];
    __syncthreads();
    float acc = gb1[t];
    for (int e = 0; e < 256; ++e)
        acc += q[e] * gw1[(size_t)(132 + e) * 512 + t];
    Qc[(size_t)n * 512 + t] = acc;
    Ctx[(size_t)n * 512 + t] = 0.f;
}

// ---------------------------------------------------------------------------
// Prep 3: transpose W2/W3/W4 (512x512 fp32 [k][n] -> fp16 [n][k])
// grid (16,16,3), block (32,8)
// ---------------------------------------------------------------------------
__global__ void transpose_w(const float* __restrict__ W2, const float* __restrict__ W3,
                            const float* __restrict__ W4, f16* __restrict__ T2,
                            f16* __restrict__ T3, f16* __restrict__ T4) {
    const int L = blockIdx.z;
    const float* W = (L == 0) ? W2 : ((L == 1) ? W3 : W4);
    f16* T = (L == 0) ? T2 : ((L == 1) ? T3 : T4);
    __shared__ float tile[32][33];
    const int bx = blockIdx.x * 32;  // n origin
    const int by = blockIdx.y * 32;  // k origin
    const int tx = threadIdx.x, ty = threadIdx.y;
    for (int r = ty; r < 32; r += 8)
        tile[r][tx] = W[(size_t)(by + r) * 512 + bx + tx];
    __syncthreads();
    for (int r = ty; r < 32; r += 8)
        T[(size_t)(bx + r) * 512 + by + tx] = (f16)tile[tx][r];
}

// ---------------------------------------------------------------------------
// Main GEMM: C(128x128 tile) = relu(A @ B + bias), A is Mchunk x 512 fp16,
// B via Bt (N x K fp16). fp32 accumulate via mfma_f32_16x16x32_f16.
// CONSTRUCT: A row p built on the fly as fp16(relu(P1[n,i] + P2[n,j] + Qc[n]))
// REDUCE: relu rows summed into Ctx (for the mean) instead of stored
// grid: (Mchunk/128)*4 blocks, block 256 (4 waves, each 64x64 via 4x4 mfma)
// LDS layout: granule (row,g) -> physical row*4 + ((g + (row>>1))&3)
//   => global_load_lds lane-contiguous AND ds_read_b128 only 2-way conflicts
// ---------------------------------------------------------------------------
template <bool CONSTRUCT, bool REDUCE>
__global__ __launch_bounds__(256) void gemm_kernel(
    const float* __restrict__ P1, const float* __restrict__ P2,
    const float* __restrict__ Qc, const f16* __restrict__ Ain,
    const f16* __restrict__ Bt, const float* __restrict__ bias,
    f16* __restrict__ Out, float* __restrict__ Ctx, int row_base) {
    const int tid = threadIdx.x;
    const int lane = tid & 63;
    const int quad = lane >> 4;
    const int l15 = lane & 15;
    const int wv = tid >> 6;
    const int wm = wv >> 1, wn = wv & 1;
    const int bm = blockIdx.x >> 2;
    const int bn = blockIdx.x & 3;

    __shared__ alignas(16) f16 lA[4096];
    __shared__ alignas(16) f16 lB[4096];
    __shared__ float lsum[128];

    if (REDUCE && tid < 128) lsum[tid] = 0.f;

    f32x4 acc[4][4];
#pragma unroll
    for (int mi = 0; mi < 4; ++mi)
#pragma unroll
        for (int ni = 0; ni < 4; ++ni)
            acc[mi][ni] = (f32x4){0.f, 0.f, 0.f, 0.f};

    for (int kt = 0; kt < 16; ++kt) {
        const int k0 = kt * 32;
        // ---- stage B (async, swizzled) ----
#pragma unroll
        for (int c = 0; c < 2; ++c) {
            int P = c * 256 + tid;
            int r = P >> 2;
            int g = ((P & 3) - (r >> 1)) & 3;
            const f16* src = Bt + (((size_t)(bn * 128 + r)) << 9) + (k0 + g * 8);
            f16* dst = &lB[((c * 256) + (tid & ~63)) * 8];
            async16(src, dst);
        }
        // ---- stage A ----
        if (CONSTRUCT) {
#pragma unroll
            for (int c = 0; c < 2; ++c) {
                int P = c * 256 + tid;
                int r = P >> 2;
                int g = ((P & 3) - (r >> 1)) & 3;
                int p = row_base + bm * 128 + r;
                int nb = p >> 12, ii = (p >> 6) & 63, jj = p & 63;
                const float* p1 = P1 + (((size_t)(nb * 64 + ii)) << 9) + k0 + g * 8;
                const float* p2 = P2 + (((size_t)(nb * 64 + jj)) << 9) + k0 + g * 8;
                const float* qq = Qc + (((size_t)nb) << 9) + k0 + g * 8;
                half8 av;
#pragma unroll
                for (int h = 0; h < 2; ++h) {
                    f32x4 x = *(const f32x4*)(p1 + h * 4);
                    f32x4 y = *(const f32x4*)(p2 + h * 4);
                    f32x4 z = *(const f32x4*)(qq + h * 4);
#pragma unroll
                    for (int e = 0; e < 4; ++e) {
                        float v = x[e] + y[e] + z[e];
                        v = fmaxf(v, 0.f);
                        av[h * 4 + e] = (f16)v;
                    }
                }
                *(half8*)&lA[P * 8] = av;
            }
        } else {
#pragma unroll
            for (int c = 0; c < 2; ++c) {
                int P = c * 256 + tid;
                int r = P >> 2;
                int g = ((P & 3) - (r >> 1)) & 3;
                const f16* src = Ain + (((size_t)(bm * 128 + r)) << 9) + (k0 + g * 8);
                f16* dst = &lA[((c * 256) + (tid & ~63)) * 8];
                async16(src, dst);
            }
        }
        __syncthreads();
        // ---- fragments ----
        half8 af[4], bfr[4];
#pragma unroll
        for (int mi = 0; mi < 4; ++mi) {
            int row = wm * 64 + mi * 16 + l15;
            int gran = row * 4 + ((quad + (row >> 1)) & 3);
            af[mi] = *(const half8*)&lA[gran * 8];
        }
#pragma unroll
        for (int ni = 0; ni < 4; ++ni) {
            int row = wn * 64 + ni * 16 + l15;
            int gran = row * 4 + ((quad + (row >> 1)) & 3);
            bfr[ni] = *(const half8*)&lB[gran * 8];
        }
#pragma unroll
        for (int mi = 0; mi < 4; ++mi)
#pragma unroll
            for (int ni = 0; ni < 4; ++ni)
                acc[mi][ni] = __builtin_amdgcn_mfma_f32_16x16x32_f16(
                    af[mi], bfr[ni], acc[mi][ni], 0, 0, 0);
        __syncthreads();
    }

    if (!REDUCE) {
#pragma unroll
        for (int mi = 0; mi < 4; ++mi) {
#pragma unroll
            for (int ni = 0; ni < 4; ++ni) {
                int col = bn * 128 + wn * 64 + ni * 16 + l15;
                float bb = bias[col];
#pragma unroll
                for (int rr = 0; rr < 4; ++rr) {
                    int row = bm * 128 + wm * 64 + mi * 16 + quad * 4 + rr;
                    float v = fmaxf(acc[mi][ni][rr] + bb, 0.f);
                    Out[(((size_t)row) << 9) + col] = (f16)v;
                }
            }
        }
    } else {
#pragma unroll
        for (int ni = 0; ni < 4; ++ni) {
            int coll = wn * 64 + ni * 16 + l15;
            float bb = bias[bn * 128 + coll];
            float s = 0.f;
#pragma unroll
            for (int mi = 0; mi < 4; ++mi)
#pragma unroll
                for (int rr = 0; rr < 4; ++rr)
                    s += fmaxf(acc[mi][ni][rr] + bb, 0.f);
            atomicAdd(&lsum[coll], s);
        }
        __syncthreads();
        if (tid < 128) {
            int nb = (row_base + bm * 128) >> 12;
            atomicAdd(&Ctx[(((size_t)nb) << 9) + bn * 128 + tid], lsum[tid]);
        }
    }
}

// ---------------------------------------------------------------------------
// f-MLP + log_softmax, all fp32. grid 64 (one per batch row), block 512.
// context is the SUM over 4096 pairs; divide here.
// ---------------------------------------------------------------------------
__global__ __launch_bounds__(512) void fmlp(const float* __restrict__ Ctx,
                                            const float* __restrict__ fw1, const float* __restrict__ fb1,
                                            const float* __restrict__ fw2, const float* __restrict__ fb2,
                                            const float* __restrict__ fw3, const float* __restrict__ fb3,
                                            float* __restrict__ out) {
    const int n = blockIdx.x;
    const int t = threadIdx.x;
    __shared__ float a[512], z[512], red0[512], red1[512];
    a[t] = Ctx[(size_t)n * 512 + t] * (1.0f / 4096.0f);
    __syncthreads();
    float acc = fb1[t];
    for (int i = 0; i < 512; ++i) acc += a[i] * fw1[(size_t)i * 512 + t];
    z[t] = fmaxf(acc, 0.f);
    __syncthreads();
    acc = fb2[t];
    for (int i = 0; i < 512; ++i) acc += z[i] * fw2[(size_t)i * 512 + t];
    a[t] = fmaxf(acc, 0.f);
    __syncthreads();
    red0[t] = a[t] * fw3[t * 2];
    red1[t] = a[t] * fw3[t * 2 + 1];
    __syncthreads();
    for (int s = 256; s > 0; s >>= 1) {
        if (t < s) { red0[t] += red0[t + s]; red1[t] += red1[t + s]; }
        __syncthreads();
    }
    if (t == 0) {
        float s0 = red0[0] + fb3[0];
        float s1 = red1[0] + fb3[1];
        float m = fmaxf(s0, s1);
        float l = logf(expf(s0 - m) + expf(s1 - m)) + m;
        out[n * 2 + 0] = s0 - l;
        out[n * 2 + 1] = s1 - l;
    }
}

// ---------------------------------------------------------------------------
extern "C" void kernel_launch(void* const* d_in, const int* in_sizes, int n_in,
                              void* d_out, int out_size, void* d_ws, size_t ws_size,
                              hipStream_t stream) {
    const float* img  = (const float*)d_in[0];
    const float* ques = (const float*)d_in[1];
    const float* gw1  = (const float*)d_in[2];
    const float* gb1  = (const float*)d_in[3];
    const float* gw2  = (const float*)d_in[4];
    const float* gb2  = (const float*)d_in[5];
    const float* gw3  = (const float*)d_in[6];
    const float* gb3  = (const float*)d_in[7];
    const float* gw4  = (const float*)d_in[8];
    const float* gb4  = (const float*)d_in[9];
    const float* fw1  = (const float*)d_in[10];
    const float* fb1  = (const float*)d_in[11];
    const float* fw2  = (const float*)d_in[12];
    const float* fb2  = (const float*)d_in[13];
    const float* fw3  = (const float*)d_in[14];
    const float* fb3  = (const float*)d_in[15];

    char* ws = (char*)d_ws;
    size_t off = 0;
    float* P1 = (float*)(ws + off); off += (size_t)4096 * 512 * 4;        // 8 MB
    float* P2 = (float*)(ws + off); off += (size_t)4096 * 512 * 4;        // 8 MB
    float* Qc = (float*)(ws + off); off += (size_t)64 * 512 * 4;          // 128 KB
    float* Ctx = (float*)(ws + off); off += (size_t)64 * 512 * 4;         // 128 KB
    f16* T2 = (f16*)(ws + off); off += (size_t)512 * 512 * 2;             // 512 KB
    f16* T3 = (f16*)(ws + off); off += (size_t)512 * 512 * 2;
    f16* T4 = (f16*)(ws + off); off += (size_t)512 * 512 * 2;
    const int MCH = 32768;                                                // rows per chunk
    f16* H2 = (f16*)(ws + off); off += (size_t)MCH * 512 * 2;             // 33.5 MB
    f16* H3 = (f16*)(ws + off); off += (size_t)MCH * 512 * 2;             // 33.5 MB

    prep_p12<<<512, 512, 0, stream>>>(img, gw1, P1, P2);
    prep_q<<<64, 512, 0, stream>>>(ques, gw1, gb1, Qc, Ctx);
    transpose_w<<<dim3(16, 16, 3), dim3(32, 8), 0, stream>>>(gw2, gw3, gw4, T2, T3, T4);

    const int grid = (MCH / 128) * 4;
    for (int ch = 0; ch < 262144 / MCH; ++ch) {
        int row_base = ch * MCH;
        gemm_kernel<true, false><<<grid, 256, 0, stream>>>(
            P1, P2, Qc, nullptr, T2, gb2, H2, nullptr, row_base);
        gemm_kernel<false, false><<<grid, 256, 0, stream>>>(
            nullptr, nullptr, nullptr, H2, T3, gb3, H3, nullptr, row_base);
        gemm_kernel<false, true><<<grid, 256, 0, stream>>>(
            nullptr, nullptr, nullptr, H3, T4, gb4, nullptr, Ctx, row_base);
    }

    fmlp<<<64, 512, 0, stream>>>(Ctx, fw1, fb1, fw2, fb2, fw3, fb3, (float*)d_out);
}

// Round 4
// 1022.368 us; speedup vs baseline: 1.0136x; 1.0136x over previous
//
#include <hip/hip_runtime.h>

typedef unsigned short u16;
typedef unsigned int u32;
typedef _Float16 f16;

using half8 = __attribute__((ext_vector_type(8))) _Float16;
using f32x4 = __attribute__((ext_vector_type(4))) float;

// swizzled granule: tile = 64 rows x 4 granules x 8 halves; 2-way-max bank aliasing
#define PG(row, g) ((row) * 4 + ((((g) + ((row) >> 1))) & 3))

// ---------------------------------------------------------------------------
// Prep 1: P1 = feats @ W1a, P2 = feats @ W1b   (4096 x 512 fp32 each)
// feats[n][cell][c] = img[n][c][cell] for c<64; c=64 -> cell/8; c=65 -> cell%8
// ---------------------------------------------------------------------------
__global__ __launch_bounds__(512) void prep_p12(const float* __restrict__ img,
                                                const float* __restrict__ gw1,
                                                float* __restrict__ P1,
                                                float* __restrict__ P2) {
    const int blk = blockIdx.x;
    const int n = blk >> 3;
    const int c0 = (blk & 7) * 8;
    const int t = threadIdx.x;
    __shared__ float feats[8][68];
    for (int idx = t; idx < 8 * 66; idx += 512) {
        int rr = idx / 66, cc = idx % 66, cell = c0 + rr;
        float v;
        if (cc < 64)       v = img[((size_t)(n * 64 + cc)) * 64 + cell];
        else if (cc == 64) v = (float)(cell >> 3);
        else               v = (float)(cell & 7);
        feats[rr][cc] = v;
    }
    __syncthreads();
    const int g = t;
    float a1[8], a2[8];
#pragma unroll
    for (int r = 0; r < 8; ++r) { a1[r] = 0.f; a2[r] = 0.f; }
    for (int c = 0; c < 66; ++c) {
        float wa = gw1[(size_t)c * 512 + g];
        float wb = gw1[(size_t)(66 + c) * 512 + g];
#pragma unroll
        for (int r = 0; r < 8; ++r) {
            a1[r] += feats[r][c] * wa;
            a2[r] += feats[r][c] * wb;
        }
    }
#pragma unroll
    for (int r = 0; r < 8; ++r) {
        P1[((size_t)(n * 64 + c0 + r)) * 512 + g] = a1[r];
        P2[((size_t)(n * 64 + c0 + r)) * 512 + g] = a2[r];
    }
}

// ---------------------------------------------------------------------------
// Prep 2: Qc[n] = ques[n] @ W1c + b1  (64 x 512 fp32); also zero context.
// ---------------------------------------------------------------------------
__global__ __launch_bounds__(512) void prep_q(const float* __restrict__ ques,
                                              const float* __restrict__ gw1,
                                              const float* __restrict__ gb1,
                                              float* __restrict__ Qc,
                                              float* __restrict__ Ctx) {
    const int n = blockIdx.x;
    const int t = threadIdx.x;
    __shared__ float q[256];
    if (t < 256) q[t] = ques[(size_t)n * 256 + t];
    __syncthreads();
    float acc = gb1[t];
    for (int e = 0; e < 256; ++e)
        acc += q[e] * gw1[(size_t)(132 + e) * 512 + t];
    Qc[(size_t)n * 512 + t] = acc;
    Ctx[(size_t)n * 512 + t] = 0.f;
}

// ---------------------------------------------------------------------------
// Prep 3: transpose W2/W3/W4 (512x512 fp32 [k][n] -> fp16 [n][k])
// ---------------------------------------------------------------------------
__global__ void transpose_w(const float* __restrict__ W2, const float* __restrict__ W3,
                            const float* __restrict__ W4, f16* __restrict__ T2,
                            f16* __restrict__ T3, f16* __restrict__ T4) {
    const int L = blockIdx.z;
    const float* W = (L == 0) ? W2 : ((L == 1) ? W3 : W4);
    f16* T = (L == 0) ? T2 : ((L == 1) ? T3 : T4);
    __shared__ float tile[32][33];
    const int bx = blockIdx.x * 32;  // n origin
    const int by = blockIdx.y * 32;  // k origin
    const int tx = threadIdx.x, ty = threadIdx.y;
    for (int r = ty; r < 32; r += 8)
        tile[r][tx] = W[(size_t)(by + r) * 512 + bx + tx];
    __syncthreads();
    for (int r = ty; r < 32; r += 8)
        T[(size_t)(bx + r) * 512 + by + tx] = (f16)tile[tx][r];
}

// ---------------------------------------------------------------------------
// Fused g-MLP. Block = 64 pair-rows (b -> n=b>>6, ii=b&63, jj=row r), grid 4096.
// All 3 layers with activations in static 64 KB LDS (16 k-tiles x 64 rows x
// 4 granules x 8 halves, swizzled via PG). Weights (T[n][k] f16) are read
// DIRECTLY from global per fragment (L2-resident, coalesced 16 rows x 64 B);
// the k-loop has no barriers. 16x16x32 f16 MFMA, fragment layouts verified
// in round 2: A[m=l15][k=quad*8+j], B[n=l15][k=quad*8+j], C: col=l15,
// row=quad*4+reg. 8 waves: wave wn owns cols wn*64..wn*64+63 (4 n-tiles),
// all 4 m-tiles. acc 4x4xf32x4 = 64 VGPRs.
// Layer 2: relu rows reduced into lsum (reusing hA) -> atomicAdd Ctx.
// ---------------------------------------------------------------------------
__global__ __launch_bounds__(512, 4) void gmlp_fused(
    const float* __restrict__ P1, const float* __restrict__ P2,
    const float* __restrict__ Qc,
    const f16* __restrict__ T2, const f16* __restrict__ T3, const f16* __restrict__ T4,
    const float* __restrict__ b2, const float* __restrict__ b3, const float* __restrict__ b4,
    float* __restrict__ Ctx) {
    __shared__ f16 hA[16 * 2048];   // 65536 B exactly

    const int t    = threadIdx.x;
    const int lane = t & 63;
    const int l15  = lane & 15;
    const int quad = lane >> 4;
    const int wn   = t >> 6;        // 0..7
    const int b    = blockIdx.x;
    const int n    = b >> 6;
    const int ii   = b & 63;

    // ---- construct hA = f16(relu(P1[ii] + P2[jj=r] + Qc[n])), 8 thr/row ----
    {
        const int r = t >> 3;       // 0..63
        const int s = t & 7;
        const float* p1 = P1 + (((size_t)(n * 64 + ii)) << 9);
        const float* p2 = P2 + (((size_t)(n * 64 + r)) << 9);
        const float* qq = Qc + (((size_t)n) << 9);
#pragma unroll
        for (int gg = 0; gg < 8; ++gg) {
            int gl = s * 8 + gg;    // global granule 0..63
            int k0 = gl * 8;        // element index 0..511
            int kt = gl >> 2, g = gl & 3;
            half8 hv;
#pragma unroll
            for (int q4 = 0; q4 < 2; ++q4) {
                f32x4 x = *(const f32x4*)(p1 + k0 + q4 * 4);
                f32x4 y = *(const f32x4*)(p2 + k0 + q4 * 4);
                f32x4 z = *(const f32x4*)(qq + k0 + q4 * 4);
#pragma unroll
                for (int e = 0; e < 4; ++e)
                    hv[q4 * 4 + e] = (f16)fmaxf(x[e] + y[e] + z[e], 0.f);
            }
            *(half8*)&hA[kt * 2048 + PG(r, g) * 8] = hv;
        }
    }
    __syncthreads();

    const f16* Tw[3]   = {T2, T3, T4};
    const float* Bs[3] = {b2, b3, b4};

    for (int layer = 0; layer < 3; ++layer) {
        const f16* __restrict__ W = Tw[layer];
        const float* bias = Bs[layer];

        f32x4 acc[4][4];
#pragma unroll
        for (int tm = 0; tm < 4; ++tm)
#pragma unroll
            for (int tn = 0; tn < 4; ++tn)
                acc[tm][tn] = (f32x4){0.f, 0.f, 0.f, 0.f};

#pragma unroll 2
        for (int kt = 0; kt < 16; ++kt) {
            half8 af[4], bf[4];
#pragma unroll
            for (int tm = 0; tm < 4; ++tm)
                af[tm] = *(const half8*)&hA[kt * 2048 + PG(tm * 16 + l15, quad) * 8];
#pragma unroll
            for (int tn = 0; tn < 4; ++tn)
                bf[tn] = *(const half8*)(W + (((size_t)(wn * 64 + tn * 16 + l15)) << 9)
                                           + kt * 32 + quad * 8);
#pragma unroll
            for (int tm = 0; tm < 4; ++tm)
#pragma unroll
                for (int tn = 0; tn < 4; ++tn)
                    acc[tm][tn] = __builtin_amdgcn_mfma_f32_16x16x32_f16(
                        af[tm], bf[tn], acc[tm][tn], 0, 0, 0);
        }
        __syncthreads();   // all hA reads of this layer complete

        if (layer < 2) {
            // write relu(acc + bias) back into hA at [row][col] (col = next k)
#pragma unroll
            for (int tn = 0; tn < 4; ++tn) {
                int col = wn * 64 + tn * 16 + l15;
                float bb = bias[col];
                int kt2 = col >> 5, g = (col >> 3) & 3, e = col & 7;
#pragma unroll
                for (int tm = 0; tm < 4; ++tm)
#pragma unroll
                    for (int reg = 0; reg < 4; ++reg) {
                        int row = tm * 16 + quad * 4 + reg;
                        hA[kt2 * 2048 + PG(row, g) * 8 + e] =
                            (f16)fmaxf(acc[tm][tn][reg] + bb, 0.f);
                    }
            }
            __syncthreads();
        } else {
            // reduce: sum relu rows per column into lsum (reuse hA storage)
            float* lsum = (float*)hA;
            lsum[t] = 0.f;
            __syncthreads();
#pragma unroll
            for (int tn = 0; tn < 4; ++tn) {
                int col = wn * 64 + tn * 16 + l15;
                float bb = bias[col];
                float s = 0.f;
#pragma unroll
                for (int tm = 0; tm < 4; ++tm)
#pragma unroll
                    for (int reg = 0; reg < 4; ++reg)
                        s += fmaxf(acc[tm][tn][reg] + bb, 0.f);
                atomicAdd(&lsum[col], s);
            }
            __syncthreads();
            atomicAdd(&Ctx[(((size_t)n) << 9) + t], lsum[t]);
        }
    }
}

// ---------------------------------------------------------------------------
// f-MLP + log_softmax, all fp32. grid 64, block 512. Ctx holds SUM; /4096 here.
// ---------------------------------------------------------------------------
__global__ __launch_bounds__(512) void fmlp(const float* __restrict__ Ctx,
                                            const float* __restrict__ fw1, const float* __restrict__ fb1,
                                            const float* __restrict__ fw2, const float* __restrict__ fb2,
                                            const float* __restrict__ fw3, const float* __restrict__ fb3,
                                            float* __restrict__ out) {
    const int n = blockIdx.x;
    const int t = threadIdx.x;
    __shared__ float a[512], z[512], red0[512], red1[512];
    a[t] = Ctx[(size_t)n * 512 + t] * (1.0f / 4096.0f);
    __syncthreads();
    float acc = fb1[t];
    for (int i = 0; i < 512; ++i) acc += a[i] * fw1[(size_t)i * 512 + t];
    z[t] = fmaxf(acc, 0.f);
    __syncthreads();
    acc = fb2[t];
    for (int i = 0; i < 512; ++i) acc += z[i] * fw2[(size_t)i * 512 + t];
    a[t] = fmaxf(acc, 0.f);
    __syncthreads();
    red0[t] = a[t] * fw3[t * 2];
    red1[t] = a[t] * fw3[t * 2 + 1];
    __syncthreads();
    for (int s = 256; s > 0; s >>= 1) {
        if (t < s) { red0[t] += red0[t + s]; red1[t] += red1[t + s]; }
        __syncthreads();
    }
    if (t == 0) {
        float s0 = red0[0] + fb3[0];
        float s1 = red1[0] + fb3[1];
        float m = fmaxf(s0, s1);
        float l = logf(expf(s0 - m) + expf(s1 - m)) + m;
        out[n * 2 + 0] = s0 - l;
        out[n * 2 + 1] = s1 - l;
    }
}

// ---------------------------------------------------------------------------
extern "C" void kernel_launch(void* const* d_in, const int* in_sizes, int n_in,
                              void* d_out, int out_size, void* d_ws, size_t ws_size,
                              hipStream_t stream) {
    const float* img  = (const float*)d_in[0];
    const float* ques = (const float*)d_in[1];
    const float* gw1  = (const float*)d_in[2];
    const float* gb1  = (const float*)d_in[3];
    const float* gw2  = (const float*)d_in[4];
    const float* gb2  = (const float*)d_in[5];
    const float* gw3  = (const float*)d_in[6];
    const float* gb3  = (const float*)d_in[7];
    const float* gw4  = (const float*)d_in[8];
    const float* gb4  = (const float*)d_in[9];
    const float* fw1  = (const float*)d_in[10];
    const float* fb1  = (const float*)d_in[11];
    const float* fw2  = (const float*)d_in[12];
    const float* fb2  = (const float*)d_in[13];
    const float* fw3  = (const float*)d_in[14];
    const float* fb3  = (const float*)d_in[15];

    char* ws = (char*)d_ws;
    size_t off = 0;
    float* P1  = (float*)(ws + off); off += (size_t)4096 * 512 * 4;   // 8 MB
    float* P2  = (float*)(ws + off); off += (size_t)4096 * 512 * 4;   // 8 MB
    float* Qc  = (float*)(ws + off); off += (size_t)64 * 512 * 4;
    float* Ctx = (float*)(ws + off); off += (size_t)64 * 512 * 4;
    f16* T2 = (f16*)(ws + off); off += (size_t)512 * 512 * 2;
    f16* T3 = (f16*)(ws + off); off += (size_t)512 * 512 * 2;
    f16* T4 = (f16*)(ws + off); off += (size_t)512 * 512 * 2;

    prep_p12<<<512, 512, 0, stream>>>(img, gw1, P1, P2);
    prep_q<<<64, 512, 0, stream>>>(ques, gw1, gb1, Qc, Ctx);
    transpose_w<<<dim3(16, 16, 3), dim3(32, 8), 0, stream>>>(gw2, gw3, gw4, T2, T3, T4);

    gmlp_fused<<<4096, 512, 0, stream>>>(P1, P2, Qc, T2, T3, T4, gb2, gb3, gb4, Ctx);

    fmlp<<<64, 512, 0, stream>>>(Ctx, fw1, fb1, fw2, fb2, fw3, fb3, (float*)d_out);
}

// Round 5
// 889.336 us; speedup vs baseline: 1.1652x; 1.1496x over previous
//
#include <hip/hip_runtime.h>

typedef unsigned short u16;
typedef unsigned int u32;
typedef _Float16 f16;

using half8 = __attribute__((ext_vector_type(8))) _Float16;
using f32x4 = __attribute__((ext_vector_type(4))) float;

__device__ __forceinline__ void async16(const void* g, void* l) {
    __builtin_amdgcn_global_load_lds(
        (const __attribute__((address_space(1))) u32*)g,
        (__attribute__((address_space(3))) u32*)l, 16, 0, 0);
}

// ---------------------------------------------------------------------------
// Prep 1: P1 = feats @ W1a, P2 = feats @ W1b   (4096 x 512 fp32 each)
// ---------------------------------------------------------------------------
__global__ __launch_bounds__(512) void prep_p12(const float* __restrict__ img,
                                                const float* __restrict__ gw1,
                                                float* __restrict__ P1,
                                                float* __restrict__ P2) {
    const int blk = blockIdx.x;
    const int n = blk >> 3;
    const int c0 = (blk & 7) * 8;
    const int t = threadIdx.x;
    __shared__ float feats[8][68];
    for (int idx = t; idx < 8 * 66; idx += 512) {
        int rr = idx / 66, cc = idx % 66, cell = c0 + rr;
        float v;
        if (cc < 64)       v = img[((size_t)(n * 64 + cc)) * 64 + cell];
        else if (cc == 64) v = (float)(cell >> 3);
        else               v = (float)(cell & 7);
        feats[rr][cc] = v;
    }
    __syncthreads();
    const int g = t;
    float a1[8], a2[8];
#pragma unroll
    for (int r = 0; r < 8; ++r) { a1[r] = 0.f; a2[r] = 0.f; }
    for (int c = 0; c < 66; ++c) {
        float wa = gw1[(size_t)c * 512 + g];
        float wb = gw1[(size_t)(66 + c) * 512 + g];
#pragma unroll
        for (int r = 0; r < 8; ++r) {
            a1[r] += feats[r][c] * wa;
            a2[r] += feats[r][c] * wb;
        }
    }
#pragma unroll
    for (int r = 0; r < 8; ++r) {
        P1[((size_t)(n * 64 + c0 + r)) * 512 + g] = a1[r];
        P2[((size_t)(n * 64 + c0 + r)) * 512 + g] = a2[r];
    }
}

// ---------------------------------------------------------------------------
// Prep 2: Qc[n] = ques[n] @ W1c + b1  (64 x 512 fp32); also zero context.
// ---------------------------------------------------------------------------
__global__ __launch_bounds__(512) void prep_q(const float* __restrict__ ques,
                                              const float* __restrict__ gw1,
                                              const float* __restrict__ gb1,
                                              float* __restrict__ Qc,
                                              float* __restrict__ Ctx) {
    const int n = blockIdx.x;
    const int t = threadIdx.x;
    __shared__ float q[256];
    if (t < 256) q[t] = ques[(size_t)n * 256 + t];
    __syncthreads();
    float acc = gb1[t];
    for (int e = 0; e < 256; ++e)
        acc += q[e] * gw1[(size_t)(132 + e) * 512 + t];
    Qc[(size_t)n * 512 + t] = acc;
    Ctx[(size_t)n * 512 + t] = 0.f;
}

// ---------------------------------------------------------------------------
// Prep 3: transpose W2/W3/W4 (512x512 fp32 [k][n] -> fp16 [n][k])
// ---------------------------------------------------------------------------
__global__ void transpose_w(const float* __restrict__ W2, const float* __restrict__ W3,
                            const float* __restrict__ W4, f16* __restrict__ T2,
                            f16* __restrict__ T3, f16* __restrict__ T4) {
    const int L = blockIdx.z;
    const float* W = (L == 0) ? W2 : ((L == 1) ? W3 : W4);
    f16* T = (L == 0) ? T2 : ((L == 1) ? T3 : T4);
    __shared__ float tile[32][33];
    const int bx = blockIdx.x * 32;  // n origin
    const int by = blockIdx.y * 32;  // k origin
    const int tx = threadIdx.x, ty = threadIdx.y;
    for (int r = ty; r < 32; r += 8)
        tile[r][tx] = W[(size_t)(by + r) * 512 + bx + tx];
    __syncthreads();
    for (int r = ty; r < 32; r += 8)
        T[(size_t)(bx + r) * 512 + by + tx] = (f16)tile[tx][r];
}

// ---------------------------------------------------------------------------
// Construct pass: H1[row_local] = f16(relu(P1[n,ii] + P2[n,jj] + Qc[n]))
// for rows [row_base, row_base + MCH). One wave = one row (64 lanes x 16 B).
// Pure streaming: HBM-bound on the 2 B/elem write; P1/P2/Qc are L2/L3-hot.
// ---------------------------------------------------------------------------
__global__ __launch_bounds__(256) void construct_h1(
    const float* __restrict__ P1, const float* __restrict__ P2,
    const float* __restrict__ Qc, f16* __restrict__ H1, int row_base) {
    const int idx = blockIdx.x * 256 + threadIdx.x;
    const int row_local = idx >> 6;
    const int k0 = (idx & 63) * 8;
    const int p = row_base + row_local;
    const int nb = p >> 12, ii = (p >> 6) & 63, jj = p & 63;
    const float* p1 = P1 + (((size_t)(nb * 64 + ii)) << 9) + k0;
    const float* p2 = P2 + (((size_t)(nb * 64 + jj)) << 9) + k0;
    const float* qq = Qc + (((size_t)nb) << 9) + k0;
    half8 hv;
#pragma unroll
    for (int q4 = 0; q4 < 2; ++q4) {
        f32x4 x = *(const f32x4*)(p1 + q4 * 4);
        f32x4 y = *(const f32x4*)(p2 + q4 * 4);
        f32x4 z = *(const f32x4*)(qq + q4 * 4);
#pragma unroll
        for (int e = 0; e < 4; ++e)
            hv[q4 * 4 + e] = (f16)fmaxf(x[e] + y[e] + z[e], 0.f);
    }
    *(half8*)(H1 + (((size_t)row_local) << 9) + k0) = hv;
}

// ---------------------------------------------------------------------------
// Pure GEMM (round-2-proven structure): C(128x128) = relu(A @ B + bias).
// A = Ain (chunk-local, MCH x 512 f16), B via Bt (N x K f16), both LDS-staged
// with async16 (swizzled granules: 2-way-max bank aliasing). 4 waves, each
// 64x64 via 4x4 16x16x32 f16 MFMA, fp32 accum.
// REDUCE: relu rows summed into Ctx instead of stored (mean numerator).
// ---------------------------------------------------------------------------
template <bool REDUCE>
__global__ __launch_bounds__(256) void gemm_kernel(
    const f16* __restrict__ Ain, const f16* __restrict__ Bt,
    const float* __restrict__ bias, f16* __restrict__ Out,
    float* __restrict__ Ctx, int row_base) {
    const int tid = threadIdx.x;
    const int lane = tid & 63;
    const int quad = lane >> 4;
    const int l15 = lane & 15;
    const int wv = tid >> 6;
    const int wm = wv >> 1, wn = wv & 1;
    const int bm = blockIdx.x >> 2;
    const int bn = blockIdx.x & 3;

    __shared__ alignas(16) f16 lA[4096];
    __shared__ alignas(16) f16 lB[4096];
    __shared__ float lsum[128];

    if (REDUCE && tid < 128) lsum[tid] = 0.f;

    f32x4 acc[4][4];
#pragma unroll
    for (int mi = 0; mi < 4; ++mi)
#pragma unroll
        for (int ni = 0; ni < 4; ++ni)
            acc[mi][ni] = (f32x4){0.f, 0.f, 0.f, 0.f};

    for (int kt = 0; kt < 16; ++kt) {
        const int k0 = kt * 32;
#pragma unroll
        for (int c = 0; c < 2; ++c) {
            int P = c * 256 + tid;
            int r = P >> 2;
            int g = ((P & 3) - (r >> 1)) & 3;
            const f16* srcB = Bt + (((size_t)(bn * 128 + r)) << 9) + (k0 + g * 8);
            async16(srcB, &lB[((c * 256) + (tid & ~63)) * 8]);
            const f16* srcA = Ain + (((size_t)(bm * 128 + r)) << 9) + (k0 + g * 8);
            async16(srcA, &lA[((c * 256) + (tid & ~63)) * 8]);
        }
        __syncthreads();
        half8 af[4], bfr[4];
#pragma unroll
        for (int mi = 0; mi < 4; ++mi) {
            int row = wm * 64 + mi * 16 + l15;
            int gran = row * 4 + ((quad + (row >> 1)) & 3);
            af[mi] = *(const half8*)&lA[gran * 8];
        }
#pragma unroll
        for (int ni = 0; ni < 4; ++ni) {
            int row = wn * 64 + ni * 16 + l15;
            int gran = row * 4 + ((quad + (row >> 1)) & 3);
            bfr[ni] = *(const half8*)&lB[gran * 8];
        }
#pragma unroll
        for (int mi = 0; mi < 4; ++mi)
#pragma unroll
            for (int ni = 0; ni < 4; ++ni)
                acc[mi][ni] = __builtin_amdgcn_mfma_f32_16x16x32_f16(
                    af[mi], bfr[ni], acc[mi][ni], 0, 0, 0);
        __syncthreads();
    }

    if (!REDUCE) {
#pragma unroll
        for (int mi = 0; mi < 4; ++mi) {
#pragma unroll
            for (int ni = 0; ni < 4; ++ni) {
                int col = bn * 128 + wn * 64 + ni * 16 + l15;
                float bb = bias[col];
#pragma unroll
                for (int rr = 0; rr < 4; ++rr) {
                    int row = bm * 128 + wm * 64 + mi * 16 + quad * 4 + rr;
                    float v = fmaxf(acc[mi][ni][rr] + bb, 0.f);
                    Out[(((size_t)row) << 9) + col] = (f16)v;
                }
            }
        }
    } else {
#pragma unroll
        for (int ni = 0; ni < 4; ++ni) {
            int coll = wn * 64 + ni * 16 + l15;
            float bb = bias[bn * 128 + coll];
            float s = 0.f;
#pragma unroll
            for (int mi = 0; mi < 4; ++mi)
#pragma unroll
                for (int rr = 0; rr < 4; ++rr)
                    s += fmaxf(acc[mi][ni][rr] + bb, 0.f);
            atomicAdd(&lsum[coll], s);
        }
        __syncthreads();
        if (tid < 128) {
            int nb = (row_base + bm * 128) >> 12;
            atomicAdd(&Ctx[(((size_t)nb) << 9) + bn * 128 + tid], lsum[tid]);
        }
    }
}

// ---------------------------------------------------------------------------
// f-MLP + log_softmax, all fp32. grid 64, block 512. Ctx holds SUM; /4096 here.
// ---------------------------------------------------------------------------
__global__ __launch_bounds__(512) void fmlp(const float* __restrict__ Ctx,
                                            const float* __restrict__ fw1, const float* __restrict__ fb1,
                                            const float* __restrict__ fw2, const float* __restrict__ fb2,
                                            const float* __restrict__ fw3, const float* __restrict__ fb3,
                                            float* __restrict__ out) {
    const int n = blockIdx.x;
    const int t = threadIdx.x;
    __shared__ float a[512], z[512], red0[512], red1[512];
    a[t] = Ctx[(size_t)n * 512 + t] * (1.0f / 4096.0f);
    __syncthreads();
    float acc = fb1[t];
    for (int i = 0; i < 512; ++i) acc += a[i] * fw1[(size_t)i * 512 + t];
    z[t] = fmaxf(acc, 0.f);
    __syncthreads();
    acc = fb2[t];
    for (int i = 0; i < 512; ++i) acc += z[i] * fw2[(size_t)i * 512 + t];
    a[t] = fmaxf(acc, 0.f);
    __syncthreads();
    red0[t] = a[t] * fw3[t * 2];
    red1[t] = a[t] * fw3[t * 2 + 1];
    __syncthreads();
    for (int s = 256; s > 0; s >>= 1) {
        if (t < s) { red0[t] += red0[t + s]; red1[t] += red1[t + s]; }
        __syncthreads();
    }
    if (t == 0) {
        float s0 = red0[0] + fb3[0];
        float s1 = red1[0] + fb3[1];
        float m = fmaxf(s0, s1);
        float l = logf(expf(s0 - m) + expf(s1 - m)) + m;
        out[n * 2 + 0] = s0 - l;
        out[n * 2 + 1] = s1 - l;
    }
}

// ---------------------------------------------------------------------------
extern "C" void kernel_launch(void* const* d_in, const int* in_sizes, int n_in,
                              void* d_out, int out_size, void* d_ws, size_t ws_size,
                              hipStream_t stream) {
    const float* img  = (const float*)d_in[0];
    const float* ques = (const float*)d_in[1];
    const float* gw1  = (const float*)d_in[2];
    const float* gb1  = (const float*)d_in[3];
    const float* gw2  = (const float*)d_in[4];
    const float* gb2  = (const float*)d_in[5];
    const float* gw3  = (const float*)d_in[6];
    const float* gb3  = (const float*)d_in[7];
    const float* gw4  = (const float*)d_in[8];
    const float* gb4  = (const float*)d_in[9];
    const float* fw1  = (const float*)d_in[10];
    const float* fb1  = (const float*)d_in[11];
    const float* fw2  = (const float*)d_in[12];
    const float* fb2  = (const float*)d_in[13];
    const float* fw3  = (const float*)d_in[14];
    const float* fb3  = (const float*)d_in[15];

    char* ws = (char*)d_ws;
    size_t off = 0;
    float* P1  = (float*)(ws + off); off += (size_t)4096 * 512 * 4;   // 8 MB
    float* P2  = (float*)(ws + off); off += (size_t)4096 * 512 * 4;   // 8 MB
    float* Qc  = (float*)(ws + off); off += (size_t)64 * 512 * 4;
    float* Ctx = (float*)(ws + off); off += (size_t)64 * 512 * 4;
    f16* T2 = (f16*)(ws + off); off += (size_t)512 * 512 * 2;
    f16* T3 = (f16*)(ws + off); off += (size_t)512 * 512 * 2;
    f16* T4 = (f16*)(ws + off); off += (size_t)512 * 512 * 2;
    const int MCH = 65536;                                            // rows/chunk
    f16* HA = (f16*)(ws + off); off += (size_t)MCH * 512 * 2;         // 67 MB
    f16* HB = (f16*)(ws + off); off += (size_t)MCH * 512 * 2;         // 67 MB

    prep_p12<<<512, 512, 0, stream>>>(img, gw1, P1, P2);
    prep_q<<<64, 512, 0, stream>>>(ques, gw1, gb1, Qc, Ctx);
    transpose_w<<<dim3(16, 16, 3), dim3(32, 8), 0, stream>>>(gw2, gw3, gw4, T2, T3, T4);

    const int cgrid = MCH * 64 / 256;        // construct: 64 thr-groups of 8 elems per row
    const int ggrid = (MCH / 128) * 4;       // 2048 blocks per GEMM dispatch
    for (int ch = 0; ch < 262144 / MCH; ++ch) {
        int row_base = ch * MCH;
        construct_h1<<<cgrid, 256, 0, stream>>>(P1, P2, Qc, HA, row_base);
        gemm_kernel<false><<<ggrid, 256, 0, stream>>>(HA, T2, gb2, HB, nullptr, row_base);
        gemm_kernel<false><<<ggrid, 256, 0, stream>>>(HB, T3, gb3, HA, nullptr, row_base);
        gemm_kernel<true ><<<ggrid, 256, 0, stream>>>(HA, T4, gb4, nullptr, Ctx, row_base);
    }

    fmlp<<<64, 512, 0, stream>>>(Ctx, fw1, fb1, fw2, fb2, fw3, fb3, (float*)d_out);
}

// Round 6
// 751.799 us; speedup vs baseline: 1.3784x; 1.1829x over previous
//
#include <hip/hip_runtime.h>

typedef unsigned short u16;
typedef unsigned int u32;
typedef _Float16 f16;

using half8 = __attribute__((ext_vector_type(8))) _Float16;
using f32x4 = __attribute__((ext_vector_type(4))) float;

__device__ __forceinline__ void async16(const void* g, void* l) {
    __builtin_amdgcn_global_load_lds(
        (const __attribute__((address_space(1))) u32*)g,
        (__attribute__((address_space(3))) u32*)l, 16, 0, 0);
}

// ---------------------------------------------------------------------------
// Prep 1: P1 = feats @ W1a, P2 = feats @ W1b   (4096 x 512 fp32 each)
// ---------------------------------------------------------------------------
__global__ __launch_bounds__(512) void prep_p12(const float* __restrict__ img,
                                                const float* __restrict__ gw1,
                                                float* __restrict__ P1,
                                                float* __restrict__ P2) {
    const int blk = blockIdx.x;
    const int n = blk >> 3;
    const int c0 = (blk & 7) * 8;
    const int t = threadIdx.x;
    __shared__ float feats[8][68];
    for (int idx = t; idx < 8 * 66; idx += 512) {
        int rr = idx / 66, cc = idx % 66, cell = c0 + rr;
        float v;
        if (cc < 64)       v = img[((size_t)(n * 64 + cc)) * 64 + cell];
        else if (cc == 64) v = (float)(cell >> 3);
        else               v = (float)(cell & 7);
        feats[rr][cc] = v;
    }
    __syncthreads();
    const int g = t;
    float a1[8], a2[8];
#pragma unroll
    for (int r = 0; r < 8; ++r) { a1[r] = 0.f; a2[r] = 0.f; }
    for (int c = 0; c < 66; ++c) {
        float wa = gw1[(size_t)c * 512 + g];
        float wb = gw1[(size_t)(66 + c) * 512 + g];
#pragma unroll
        for (int r = 0; r < 8; ++r) {
            a1[r] += feats[r][c] * wa;
            a2[r] += feats[r][c] * wb;
        }
    }
#pragma unroll
    for (int r = 0; r < 8; ++r) {
        P1[((size_t)(n * 64 + c0 + r)) * 512 + g] = a1[r];
        P2[((size_t)(n * 64 + c0 + r)) * 512 + g] = a2[r];
    }
}

// ---------------------------------------------------------------------------
// Prep 2: Qc[n] = ques[n] @ W1c + b1  (64 x 512 fp32); also zero context.
// ---------------------------------------------------------------------------
__global__ __launch_bounds__(512) void prep_q(const float* __restrict__ ques,
                                              const float* __restrict__ gw1,
                                              const float* __restrict__ gb1,
                                              float* __restrict__ Qc,
                                              float* __restrict__ Ctx) {
    const int n = blockIdx.x;
    const int t = threadIdx.x;
    __shared__ float q[256];
    if (t < 256) q[t] = ques[(size_t)n * 256 + t];
    __syncthreads();
    float acc = gb1[t];
    for (int e = 0; e < 256; ++e)
        acc += q[e] * gw1[(size_t)(132 + e) * 512 + t];
    Qc[(size_t)n * 512 + t] = acc;
    Ctx[(size_t)n * 512 + t] = 0.f;
}

// ---------------------------------------------------------------------------
// Prep 3: transpose W2/W3/W4 (512x512 fp32 [k][n] -> fp16 [n][k])
// ---------------------------------------------------------------------------
__global__ void transpose_w(const float* __restrict__ W2, const float* __restrict__ W3,
                            const float* __restrict__ W4, f16* __restrict__ T2,
                            f16* __restrict__ T3, f16* __restrict__ T4) {
    const int L = blockIdx.z;
    const float* W = (L == 0) ? W2 : ((L == 1) ? W3 : W4);
    f16* T = (L == 0) ? T2 : ((L == 1) ? T3 : T4);
    __shared__ float tile[32][33];
    const int bx = blockIdx.x * 32;  // n origin
    const int by = blockIdx.y * 32;  // k origin
    const int tx = threadIdx.x, ty = threadIdx.y;
    for (int r = ty; r < 32; r += 8)
        tile[r][tx] = W[(size_t)(by + r) * 512 + bx + tx];
    __syncthreads();
    for (int r = ty; r < 32; r += 8)
        T[(size_t)(bx + r) * 512 + by + tx] = (f16)tile[tx][r];
}

// ---------------------------------------------------------------------------
// Construct pass: H1[row_local] = f16(relu(P1[n,ii] + P2[n,jj] + Qc[n])).
// XCD-pinned: 128-row stripe bm is handled by blocks with blockIdx%8 == bm%8
// (same pinning as the GEMMs below), so H1 rows are L2-local to their
// consumer GEMM blocks. 256 thr = 4 rows x 64 lanes x 16 B.
// grid 16384: cb -> x=cb&7, s=cb>>3, j=s&31 (sub-block), bm=(s>>5)*8+x.
// ---------------------------------------------------------------------------
__global__ __launch_bounds__(256) void construct_h1(
    const float* __restrict__ P1, const float* __restrict__ P2,
    const float* __restrict__ Qc, f16* __restrict__ H1, int row_base) {
    const int cb = blockIdx.x;
    const int x  = cb & 7;
    const int s  = cb >> 3;
    const int j  = s & 31;
    const int bm = (s >> 5) * 8 + x;
    const int row_local = bm * 128 + j * 4 + (threadIdx.x >> 6);
    const int k0 = (threadIdx.x & 63) * 8;
    const int p = row_base + row_local;
    const int nb = p >> 12, ii = (p >> 6) & 63, jj = p & 63;
    const float* p1 = P1 + (((size_t)(nb * 64 + ii)) << 9) + k0;
    const float* p2 = P2 + (((size_t)(nb * 64 + jj)) << 9) + k0;
    const float* qq = Qc + (((size_t)nb) << 9) + k0;
    half8 hv;
#pragma unroll
    for (int q4 = 0; q4 < 2; ++q4) {
        f32x4 xx = *(const f32x4*)(p1 + q4 * 4);
        f32x4 yy = *(const f32x4*)(p2 + q4 * 4);
        f32x4 zz = *(const f32x4*)(qq + q4 * 4);
#pragma unroll
        for (int e = 0; e < 4; ++e)
            hv[q4 * 4 + e] = (f16)fmaxf(xx[e] + yy[e] + zz[e], 0.f);
    }
    *(half8*)(H1 + (((size_t)row_local) << 9) + k0) = hv;
}

// ---------------------------------------------------------------------------
// Pure GEMM (round-2/5-proven internals): C(128x128) = relu(A @ B + bias).
// XCD-pinned swizzle: b -> x=b&7 (XCD), s=b>>3, bn=s&3 (FAST-varying so the
// 4 column-blocks of one A-stripe run back-to-back on one XCD -> A read once
// from HBM, 3x from that XCD's L2), bm=(s>>2)*8+x (stripe pinned to XCD
// bm%8 across ALL dispatches -> H produce/consume row locality).
// A/B LDS-staged via async16, swizzled granules (2-way-max bank aliasing).
// 4 waves, each 64x64 via 4x4 16x16x32 f16 MFMA, fp32 accum.
// REDUCE: relu rows summed into Ctx instead of stored (mean numerator).
// ---------------------------------------------------------------------------
template <bool REDUCE>
__global__ __launch_bounds__(256) void gemm_kernel(
    const f16* __restrict__ Ain, const f16* __restrict__ Bt,
    const float* __restrict__ bias, f16* __restrict__ Out,
    float* __restrict__ Ctx, int row_base) {
    const int tid = threadIdx.x;
    const int lane = tid & 63;
    const int quad = lane >> 4;
    const int l15 = lane & 15;
    const int wv = tid >> 6;
    const int wm = wv >> 1, wn = wv & 1;
    const int b  = blockIdx.x;
    const int x  = b & 7;
    const int s  = b >> 3;
    const int bn = s & 3;
    const int bm = (s >> 2) * 8 + x;

    __shared__ alignas(16) f16 lA[4096];
    __shared__ alignas(16) f16 lB[4096];
    __shared__ float lsum[128];

    if (REDUCE && tid < 128) lsum[tid] = 0.f;

    f32x4 acc[4][4];
#pragma unroll
    for (int mi = 0; mi < 4; ++mi)
#pragma unroll
        for (int ni = 0; ni < 4; ++ni)
            acc[mi][ni] = (f32x4){0.f, 0.f, 0.f, 0.f};

    for (int kt = 0; kt < 16; ++kt) {
        const int k0 = kt * 32;
#pragma unroll
        for (int c = 0; c < 2; ++c) {
            int P = c * 256 + tid;
            int r = P >> 2;
            int g = ((P & 3) - (r >> 1)) & 3;
            const f16* srcB = Bt + (((size_t)(bn * 128 + r)) << 9) + (k0 + g * 8);
            async16(srcB, &lB[((c * 256) + (tid & ~63)) * 8]);
            const f16* srcA = Ain + (((size_t)(bm * 128 + r)) << 9) + (k0 + g * 8);
            async16(srcA, &lA[((c * 256) + (tid & ~63)) * 8]);
        }
        __syncthreads();
        half8 af[4], bfr[4];
#pragma unroll
        for (int mi = 0; mi < 4; ++mi) {
            int row = wm * 64 + mi * 16 + l15;
            int gran = row * 4 + ((quad + (row >> 1)) & 3);
            af[mi] = *(const half8*)&lA[gran * 8];
        }
#pragma unroll
        for (int ni = 0; ni < 4; ++ni) {
            int row = wn * 64 + ni * 16 + l15;
            int gran = row * 4 + ((quad + (row >> 1)) & 3);
            bfr[ni] = *(const half8*)&lB[gran * 8];
        }
#pragma unroll
        for (int mi = 0; mi < 4; ++mi)
#pragma unroll
            for (int ni = 0; ni < 4; ++ni)
                acc[mi][ni] = __builtin_amdgcn_mfma_f32_16x16x32_f16(
                    af[mi], bfr[ni], acc[mi][ni], 0, 0, 0);
        __syncthreads();
    }

    if (!REDUCE) {
#pragma unroll
        for (int mi = 0; mi < 4; ++mi) {
#pragma unroll
            for (int ni = 0; ni < 4; ++ni) {
                int col = bn * 128 + wn * 64 + ni * 16 + l15;
                float bb = bias[col];
#pragma unroll
                for (int rr = 0; rr < 4; ++rr) {
                    int row = bm * 128 + wm * 64 + mi * 16 + quad * 4 + rr;
                    float v = fmaxf(acc[mi][ni][rr] + bb, 0.f);
                    Out[(((size_t)row) << 9) + col] = (f16)v;
                }
            }
        }
    } else {
#pragma unroll
        for (int ni = 0; ni < 4; ++ni) {
            int coll = wn * 64 + ni * 16 + l15;
            float bb = bias[bn * 128 + coll];
            float ssum = 0.f;
#pragma unroll
            for (int mi = 0; mi < 4; ++mi)
#pragma unroll
                for (int rr = 0; rr < 4; ++rr)
                    ssum += fmaxf(acc[mi][ni][rr] + bb, 0.f);
            atomicAdd(&lsum[coll], ssum);
        }
        __syncthreads();
        if (tid < 128) {
            int nb = (row_base + bm * 128) >> 12;
            atomicAdd(&Ctx[(((size_t)nb) << 9) + bn * 128 + tid], lsum[tid]);
        }
    }
}

// ---------------------------------------------------------------------------
// f-MLP + log_softmax, all fp32. grid 64, block 512. Ctx holds SUM; /4096 here.
// ---------------------------------------------------------------------------
__global__ __launch_bounds__(512) void fmlp(const float* __restrict__ Ctx,
                                            const float* __restrict__ fw1, const float* __restrict__ fb1,
                                            const float* __restrict__ fw2, const float* __restrict__ fb2,
                                            const float* __restrict__ fw3, const float* __restrict__ fb3,
                                            float* __restrict__ out) {
    const int n = blockIdx.x;
    const int t = threadIdx.x;
    __shared__ float a[512], z[512], red0[512], red1[512];
    a[t] = Ctx[(size_t)n * 512 + t] * (1.0f / 4096.0f);
    __syncthreads();
    float acc = fb1[t];
    for (int i = 0; i < 512; ++i) acc += a[i] * fw1[(size_t)i * 512 + t];
    z[t] = fmaxf(acc, 0.f);
    __syncthreads();
    acc = fb2[t];
    for (int i = 0; i < 512; ++i) acc += z[i] * fw2[(size_t)i * 512 + t];
    a[t] = fmaxf(acc, 0.f);
    __syncthreads();
    red0[t] = a[t] * fw3[t * 2];
    red1[t] = a[t] * fw3[t * 2 + 1];
    __syncthreads();
    for (int s = 256; s > 0; s >>= 1) {
        if (t < s) { red0[t] += red0[t + s]; red1[t] += red1[t + s]; }
        __syncthreads();
    }
    if (t == 0) {
        float s0 = red0[0] + fb3[0];
        float s1 = red1[0] + fb3[1];
        float m = fmaxf(s0, s1);
        float l = logf(expf(s0 - m) + expf(s1 - m)) + m;
        out[n * 2 + 0] = s0 - l;
        out[n * 2 + 1] = s1 - l;
    }
}

// ---------------------------------------------------------------------------
extern "C" void kernel_launch(void* const* d_in, const int* in_sizes, int n_in,
                              void* d_out, int out_size, void* d_ws, size_t ws_size,
                              hipStream_t stream) {
    const float* img  = (const float*)d_in[0];
    const float* ques = (const float*)d_in[1];
    const float* gw1  = (const float*)d_in[2];
    const float* gb1  = (const float*)d_in[3];
    const float* gw2  = (const float*)d_in[4];
    const float* gb2  = (const float*)d_in[5];
    const float* gw3  = (const float*)d_in[6];
    const float* gb3  = (const float*)d_in[7];
    const float* gw4  = (const float*)d_in[8];
    const float* gb4  = (const float*)d_in[9];
    const float* fw1  = (const float*)d_in[10];
    const float* fb1  = (const float*)d_in[11];
    const float* fw2  = (const float*)d_in[12];
    const float* fb2  = (const float*)d_in[13];
    const float* fw3  = (const float*)d_in[14];
    const float* fb3  = (const float*)d_in[15];

    char* ws = (char*)d_ws;
    size_t off = 0;
    float* P1  = (float*)(ws + off); off += (size_t)4096 * 512 * 4;   // 8 MB
    float* P2  = (float*)(ws + off); off += (size_t)4096 * 512 * 4;   // 8 MB
    float* Qc  = (float*)(ws + off); off += (size_t)64 * 512 * 4;
    float* Ctx = (float*)(ws + off); off += (size_t)64 * 512 * 4;
    f16* T2 = (f16*)(ws + off); off += (size_t)512 * 512 * 2;
    f16* T3 = (f16*)(ws + off); off += (size_t)512 * 512 * 2;
    f16* T4 = (f16*)(ws + off); off += (size_t)512 * 512 * 2;
    const int MCH = 65536;                                            // rows/chunk
    f16* HA = (f16*)(ws + off); off += (size_t)MCH * 512 * 2;         // 67 MB
    f16* HB = (f16*)(ws + off); off += (size_t)MCH * 512 * 2;         // 67 MB

    prep_p12<<<512, 512, 0, stream>>>(img, gw1, P1, P2);
    prep_q<<<64, 512, 0, stream>>>(ques, gw1, gb1, Qc, Ctx);
    transpose_w<<<dim3(16, 16, 3), dim3(32, 8), 0, stream>>>(gw2, gw3, gw4, T2, T3, T4);

    const int cgrid = MCH * 64 / 256;        // 16384 construct blocks
    const int ggrid = (MCH / 128) * 4;       // 2048 GEMM blocks per dispatch
    for (int ch = 0; ch < 262144 / MCH; ++ch) {
        int row_base = ch * MCH;
        construct_h1<<<cgrid, 256, 0, stream>>>(P1, P2, Qc, HA, row_base);
        gemm_kernel<false><<<ggrid, 256, 0, stream>>>(HA, T2, gb2, HB, nullptr, row_base);
        gemm_kernel<false><<<ggrid, 256, 0, stream>>>(HB, T3, gb3, HA, nullptr, row_base);
        gemm_kernel<true ><<<ggrid, 256, 0, stream>>>(HA, T4, gb4, nullptr, Ctx, row_base);
    }

    fmlp<<<64, 512, 0, stream>>>(Ctx, fw1, fb1, fw2, fb2, fw3, fb3, (float*)d_out);
}

// Round 7
// 664.059 us; speedup vs baseline: 1.5605x; 1.1321x over previous
//
#include <hip/hip_runtime.h>

typedef unsigned short u16;
typedef unsigned int u32;
typedef _Float16 f16;

using half8 = __attribute__((ext_vector_type(8))) _Float16;
using f32x4 = __attribute__((ext_vector_type(4))) float;

__device__ __forceinline__ void async16(const void* g, void* l) {
    __builtin_amdgcn_global_load_lds(
        (const __attribute__((address_space(1))) u32*)g,
        (__attribute__((address_space(3))) u32*)l, 16, 0, 0);
}

// ---------------------------------------------------------------------------
// Prep 1: P1 = feats @ W1a, P2 = feats @ W1b   (4096 x 512 fp32 each)
// ---------------------------------------------------------------------------
__global__ __launch_bounds__(512) void prep_p12(const float* __restrict__ img,
                                                const float* __restrict__ gw1,
                                                float* __restrict__ P1,
                                                float* __restrict__ P2) {
    const int blk = blockIdx.x;
    const int n = blk >> 3;
    const int c0 = (blk & 7) * 8;
    const int t = threadIdx.x;
    __shared__ float feats[8][68];
    for (int idx = t; idx < 8 * 66; idx += 512) {
        int rr = idx / 66, cc = idx % 66, cell = c0 + rr;
        float v;
        if (cc < 64)       v = img[((size_t)(n * 64 + cc)) * 64 + cell];
        else if (cc == 64) v = (float)(cell >> 3);
        else               v = (float)(cell & 7);
        feats[rr][cc] = v;
    }
    __syncthreads();
    const int g = t;
    float a1[8], a2[8];
#pragma unroll
    for (int r = 0; r < 8; ++r) { a1[r] = 0.f; a2[r] = 0.f; }
    for (int c = 0; c < 66; ++c) {
        float wa = gw1[(size_t)c * 512 + g];
        float wb = gw1[(size_t)(66 + c) * 512 + g];
#pragma unroll
        for (int r = 0; r < 8; ++r) {
            a1[r] += feats[r][c] * wa;
            a2[r] += feats[r][c] * wb;
        }
    }
#pragma unroll
    for (int r = 0; r < 8; ++r) {
        P1[((size_t)(n * 64 + c0 + r)) * 512 + g] = a1[r];
        P2[((size_t)(n * 64 + c0 + r)) * 512 + g] = a2[r];
    }
}

// ---------------------------------------------------------------------------
// Prep 2: Qc[n] = ques[n] @ W1c + b1  (64 x 512 fp32); also zero context.
// ---------------------------------------------------------------------------
__global__ __launch_bounds__(512) void prep_q(const float* __restrict__ ques,
                                              const float* __restrict__ gw1,
                                              const float* __restrict__ gb1,
                                              float* __restrict__ Qc,
                                              float* __restrict__ Ctx) {
    const int n = blockIdx.x;
    const int t = threadIdx.x;
    __shared__ float q[256];
    if (t < 256) q[t] = ques[(size_t)n * 256 + t];
    __syncthreads();
    float acc = gb1[t];
    for (int e = 0; e < 256; ++e)
        acc += q[e] * gw1[(size_t)(132 + e) * 512 + t];
    Qc[(size_t)n * 512 + t] = acc;
    Ctx[(size_t)n * 512 + t] = 0.f;
}

// ---------------------------------------------------------------------------
// Prep 3: transpose W2/W3/W4 (512x512 fp32 [k][n] -> fp16 [n][k])
// ---------------------------------------------------------------------------
__global__ void transpose_w(const float* __restrict__ W2, const float* __restrict__ W3,
                            const float* __restrict__ W4, f16* __restrict__ T2,
                            f16* __restrict__ T3, f16* __restrict__ T4) {
    const int L = blockIdx.z;
    const float* W = (L == 0) ? W2 : ((L == 1) ? W3 : W4);
    f16* T = (L == 0) ? T2 : ((L == 1) ? T3 : T4);
    __shared__ float tile[32][33];
    const int bx = blockIdx.x * 32;  // n origin
    const int by = blockIdx.y * 32;  // k origin
    const int tx = threadIdx.x, ty = threadIdx.y;
    for (int r = ty; r < 32; r += 8)
        tile[r][tx] = W[(size_t)(by + r) * 512 + bx + tx];
    __syncthreads();
    for (int r = ty; r < 32; r += 8)
        T[(size_t)(bx + r) * 512 + by + tx] = (f16)tile[tx][r];
}

// ---------------------------------------------------------------------------
// Construct pass: H1[row_local] = f16(relu(P1[n,ii] + P2[n,jj] + Qc[n])).
// XCD-pinned to 256-row stripes: stripe bm handled by blocks with cb%8==bm%8,
// matching the GEMM pinning below. 256 thr = 4 rows x 64 lanes x 16 B.
// grid 16384: cb -> x=cb&7, s=cb>>3, j=s&63, bm=(s>>6)*8+x (0..255).
// ---------------------------------------------------------------------------
__global__ __launch_bounds__(256) void construct_h1(
    const float* __restrict__ P1, const float* __restrict__ P2,
    const float* __restrict__ Qc, f16* __restrict__ H1, int row_base) {
    const int cb = blockIdx.x;
    const int x  = cb & 7;
    const int s  = cb >> 3;
    const int j  = s & 63;
    const int bm = (s >> 6) * 8 + x;
    const int row_local = bm * 256 + j * 4 + (threadIdx.x >> 6);
    const int k0 = (threadIdx.x & 63) * 8;
    const int p = row_base + row_local;
    const int nb = p >> 12, ii = (p >> 6) & 63, jj = p & 63;
    const float* p1 = P1 + (((size_t)(nb * 64 + ii)) << 9) + k0;
    const float* p2 = P2 + (((size_t)(nb * 64 + jj)) << 9) + k0;
    const float* qq = Qc + (((size_t)nb) << 9) + k0;
    half8 hv;
#pragma unroll
    for (int q4 = 0; q4 < 2; ++q4) {
        f32x4 xx = *(const f32x4*)(p1 + q4 * 4);
        f32x4 yy = *(const f32x4*)(p2 + q4 * 4);
        f32x4 zz = *(const f32x4*)(qq + q4 * 4);
#pragma unroll
        for (int e = 0; e < 4; ++e)
            hv[q4 * 4 + e] = (f16)fmaxf(xx[e] + yy[e] + zz[e], 0.f);
    }
    *(half8*)(H1 + (((size_t)row_local) << 9) + k0) = hv;
}

// ---------------------------------------------------------------------------
// GEMM v3: C(256x128 tile) = relu(A @ B + bias). 4 waves, wave-tile 128x64
// (8m x 4n 16x16x32 tiles, acc=128 VGPRs) -> 25% less LDS fragment traffic
// than 64x64. BK=64 (8 k-iterations, 16 barriers/block vs 32).
// XCD-pinned swizzle: b -> x=b&7 (XCD), s=b>>3, bn=s&3 (fast -> A-stripe's 4
// column-blocks run back-to-back on one XCD), bm=(s>>2)*8+x (stripe pinned
// to XCD bm%8 across construct + all 3 GEMMs).
// LDS granules (16 B): phys = r*8 + ((gc + r)&7)  [gc = k-granule 0..7]
//   - staging decode: r=p>>3, gc=((p&7)-r)&7 -> lane-contiguous async16 ok
//   - frag reads: 16 lanes (r consecutive) spread all 8 bank-groups, 2-way max
// REDUCE: shfl-butterfly row-sum (relu), 1 LDS atomic per wave-col, then Ctx.
// ---------------------------------------------------------------------------
template <bool REDUCE>
__global__ __launch_bounds__(256, 2) void gemm_kernel(
    const f16* __restrict__ Ain, const f16* __restrict__ Bt,
    const float* __restrict__ bias, f16* __restrict__ Out,
    float* __restrict__ Ctx, int row_base) {
    const int tid = threadIdx.x;
    const int lane = tid & 63;
    const int quad = lane >> 4;
    const int l15 = lane & 15;
    const int wv = tid >> 6;
    const int wm = wv >> 1, wn = wv & 1;
    const int b  = blockIdx.x;
    const int x  = b & 7;
    const int s  = b >> 3;
    const int bn = s & 3;
    const int bm = (s >> 2) * 8 + x;     // 0..255

    __shared__ alignas(16) f16 lA[256 * 64];   // 32 KB
    __shared__ alignas(16) f16 lB[128 * 64];   // 16 KB
    __shared__ float lsum[128];

    if (REDUCE && tid < 128) lsum[tid] = 0.f;

    f32x4 acc[8][4];
#pragma unroll
    for (int mi = 0; mi < 8; ++mi)
#pragma unroll
        for (int ni = 0; ni < 4; ++ni)
            acc[mi][ni] = (f32x4){0.f, 0.f, 0.f, 0.f};

    for (int kt = 0; kt < 8; ++kt) {
        const int k0 = kt * 64;
        // ---- stage A (2048 granules) ----
#pragma unroll
        for (int c = 0; c < 8; ++c) {
            int p = c * 256 + tid;
            int r = p >> 3;
            int gc = ((p & 7) - r) & 7;
            const f16* srcA = Ain + (((size_t)(bm * 256 + r)) << 9) + k0 + gc * 8;
            async16(srcA, &lA[(c * 256 + (tid & ~63)) * 8]);
        }
        // ---- stage B (1024 granules) ----
#pragma unroll
        for (int c = 0; c < 4; ++c) {
            int p = c * 256 + tid;
            int r = p >> 3;
            int gc = ((p & 7) - r) & 7;
            const f16* srcB = Bt + (((size_t)(bn * 128 + r)) << 9) + k0 + gc * 8;
            async16(srcB, &lB[(c * 256 + (tid & ~63)) * 8]);
        }
        __syncthreads();
#pragma unroll
        for (int ks = 0; ks < 2; ++ks) {
            half8 af[8], bf[4];
            const int gc = ks * 4 + quad;
#pragma unroll
            for (int mi = 0; mi < 8; ++mi) {
                int r = wm * 128 + mi * 16 + l15;
                af[mi] = *(const half8*)&lA[(r * 8 + ((gc + r) & 7)) * 8];
            }
#pragma unroll
            for (int ni = 0; ni < 4; ++ni) {
                int r = wn * 64 + ni * 16 + l15;
                bf[ni] = *(const half8*)&lB[(r * 8 + ((gc + r) & 7)) * 8];
            }
#pragma unroll
            for (int mi = 0; mi < 8; ++mi)
#pragma unroll
                for (int ni = 0; ni < 4; ++ni)
                    acc[mi][ni] = __builtin_amdgcn_mfma_f32_16x16x32_f16(
                        af[mi], bf[ni], acc[mi][ni], 0, 0, 0);
        }
        __syncthreads();
    }

    if (!REDUCE) {
#pragma unroll
        for (int mi = 0; mi < 8; ++mi) {
#pragma unroll
            for (int ni = 0; ni < 4; ++ni) {
                int col = bn * 128 + wn * 64 + ni * 16 + l15;
                float bb = bias[col];
#pragma unroll
                for (int rr = 0; rr < 4; ++rr) {
                    int row = bm * 256 + wm * 128 + mi * 16 + quad * 4 + rr;
                    float v = fmaxf(acc[mi][ni][rr] + bb, 0.f);
                    Out[(((size_t)row) << 9) + col] = (f16)v;
                }
            }
        }
    } else {
#pragma unroll
        for (int ni = 0; ni < 4; ++ni) {
            int coll = wn * 64 + ni * 16 + l15;
            float bb = bias[bn * 128 + coll];
            float ssum = 0.f;
#pragma unroll
            for (int mi = 0; mi < 8; ++mi)
#pragma unroll
                for (int rr = 0; rr < 4; ++rr)
                    ssum += fmaxf(acc[mi][ni][rr] + bb, 0.f);
            // sum across the 4 quads (rows 4q..4q+3 of each 16-row tile)
            ssum += __shfl_xor(ssum, 16, 64);
            ssum += __shfl_xor(ssum, 32, 64);
            if (quad == 0) atomicAdd(&lsum[coll], ssum);
        }
        __syncthreads();
        if (tid < 128) {
            int nb = (row_base + bm * 256) >> 12;
            atomicAdd(&Ctx[(((size_t)nb) << 9) + bn * 128 + tid], lsum[tid]);
        }
    }
}

// ---------------------------------------------------------------------------
// f-MLP + log_softmax, all fp32. grid 64, block 512. Ctx holds SUM; /4096 here.
// ---------------------------------------------------------------------------
__global__ __launch_bounds__(512) void fmlp(const float* __restrict__ Ctx,
                                            const float* __restrict__ fw1, const float* __restrict__ fb1,
                                            const float* __restrict__ fw2, const float* __restrict__ fb2,
                                            const float* __restrict__ fw3, const float* __restrict__ fb3,
                                            float* __restrict__ out) {
    const int n = blockIdx.x;
    const int t = threadIdx.x;
    __shared__ float a[512], z[512], red0[512], red1[512];
    a[t] = Ctx[(size_t)n * 512 + t] * (1.0f / 4096.0f);
    __syncthreads();
    float acc = fb1[t];
    for (int i = 0; i < 512; ++i) acc += a[i] * fw1[(size_t)i * 512 + t];
    z[t] = fmaxf(acc, 0.f);
    __syncthreads();
    acc = fb2[t];
    for (int i = 0; i < 512; ++i) acc += z[i] * fw2[(size_t)i * 512 + t];
    a[t] = fmaxf(acc, 0.f);
    __syncthreads();
    red0[t] = a[t] * fw3[t * 2];
    red1[t] = a[t] * fw3[t * 2 + 1];
    __syncthreads();
    for (int s = 256; s > 0; s >>= 1) {
        if (t < s) { red0[t] += red0[t + s]; red1[t] += red1[t + s]; }
        __syncthreads();
    }
    if (t == 0) {
        float s0 = red0[0] + fb3[0];
        float s1 = red1[0] + fb3[1];
        float m = fmaxf(s0, s1);
        float l = logf(expf(s0 - m) + expf(s1 - m)) + m;
        out[n * 2 + 0] = s0 - l;
        out[n * 2 + 1] = s1 - l;
    }
}

// ---------------------------------------------------------------------------
extern "C" void kernel_launch(void* const* d_in, const int* in_sizes, int n_in,
                              void* d_out, int out_size, void* d_ws, size_t ws_size,
                              hipStream_t stream) {
    const float* img  = (const float*)d_in[0];
    const float* ques = (const float*)d_in[1];
    const float* gw1  = (const float*)d_in[2];
    const float* gb1  = (const float*)d_in[3];
    const float* gw2  = (const float*)d_in[4];
    const float* gb2  = (const float*)d_in[5];
    const float* gw3  = (const float*)d_in[6];
    const float* gb3  = (const float*)d_in[7];
    const float* gw4  = (const float*)d_in[8];
    const float* gb4  = (const float*)d_in[9];
    const float* fw1  = (const float*)d_in[10];
    const float* fb1  = (const float*)d_in[11];
    const float* fw2  = (const float*)d_in[12];
    const float* fb2  = (const float*)d_in[13];
    const float* fw3  = (const float*)d_in[14];
    const float* fb3  = (const float*)d_in[15];

    char* ws = (char*)d_ws;
    size_t off = 0;
    float* P1  = (float*)(ws + off); off += (size_t)4096 * 512 * 4;   // 8 MB
    float* P2  = (float*)(ws + off); off += (size_t)4096 * 512 * 4;   // 8 MB
    float* Qc  = (float*)(ws + off); off += (size_t)64 * 512 * 4;
    float* Ctx = (float*)(ws + off); off += (size_t)64 * 512 * 4;
    f16* T2 = (f16*)(ws + off); off += (size_t)512 * 512 * 2;
    f16* T3 = (f16*)(ws + off); off += (size_t)512 * 512 * 2;
    f16* T4 = (f16*)(ws + off); off += (size_t)512 * 512 * 2;
    const int MCH = 65536;                                            // rows/chunk
    f16* HA = (f16*)(ws + off); off += (size_t)MCH * 512 * 2;         // 67 MB
    f16* HB = (f16*)(ws + off); off += (size_t)MCH * 512 * 2;         // 67 MB

    prep_p12<<<512, 512, 0, stream>>>(img, gw1, P1, P2);
    prep_q<<<64, 512, 0, stream>>>(ques, gw1, gb1, Qc, Ctx);
    transpose_w<<<dim3(16, 16, 3), dim3(32, 8), 0, stream>>>(gw2, gw3, gw4, T2, T3, T4);

    const int cgrid = MCH * 64 / 256;        // 16384 construct blocks
    const int ggrid = (MCH / 256) * 4;       // 1024 GEMM blocks per dispatch
    for (int ch = 0; ch < 262144 / MCH; ++ch) {
        int row_base = ch * MCH;
        construct_h1<<<cgrid, 256, 0, stream>>>(P1, P2, Qc, HA, row_base);
        gemm_kernel<false><<<ggrid, 256, 0, stream>>>(HA, T2, gb2, HB, nullptr, row_base);
        gemm_kernel<false><<<ggrid, 256, 0, stream>>>(HB, T3, gb3, HA, nullptr, row_base);
        gemm_kernel<true ><<<ggrid, 256, 0, stream>>>(HA, T4, gb4, nullptr, Ctx, row_base);
    }

    fmlp<<<64, 512, 0, stream>>>(Ctx, fw1, fb1, fw2, fb2, fw3, fb3, (float*)d_out);
}